// Round 6
// baseline (985.129 us; speedup 1.0000x reference)
//
#include <hip/hip_runtime.h>
#include <hip/hip_bf16.h>

// GIN net, round 5 (resubmit after GPU-acquisition timeout): two-level bucketed
// CSR build (replaces atomic fill: 85MB scattered writes -> ~10MB bucket-local
// writes), prep folded into fused MLP, single combined memset. Register-tiled
// fused MLP + vectorized gather as r4.

#define HD 64

// ================= CSR build: two-level bucket sort =================
// bucket b = dst >> 7 (128 nodes/bucket); NB = ceil(N/128) <= 1024
__global__ void bucket_hist_kernel(const int* __restrict__ ei, int* __restrict__ bcnt, int E) {
    int e = blockIdx.x * blockDim.x + threadIdx.x;
    if (e >= E) return;
    atomicAdd(&bcnt[ei[E + e] >> 7], 1);
}

__global__ void bucket_scan_kernel(const int* __restrict__ bcnt, int* __restrict__ boff, int NB) {
    __shared__ int s[1024];
    int tid = threadIdx.x;
    s[tid] = (tid < NB) ? bcnt[tid] : 0;
    __syncthreads();
    for (int off = 1; off < 1024; off <<= 1) {
        int v = (tid >= off) ? s[tid - off] : 0;
        __syncthreads();
        s[tid] += v;
        __syncthreads();
    }
    if (tid == 0) boff[0] = 0;
    if (tid < NB) boff[tid + 1] = s[tid];
}

// pack src | (dst&127)<<24 ; requires N < 2^24
__global__ void bucket_scatter_kernel(const int* __restrict__ ei, const int* __restrict__ boff,
                                      int* __restrict__ bcur, int* __restrict__ bpack, int E) {
    int e = blockIdx.x * blockDim.x + threadIdx.x;
    if (e >= E) return;
    int src = ei[e], dst = ei[E + e];
    int b = dst >> 7;
    int pos = atomicAdd(&bcur[b], 1);
    bpack[boff[b] + pos] = src | ((dst & 127) << 24);
}

// one block per bucket: local degree count, LDS scan, coalesced row_start,
// CSR writes confined to the bucket's contiguous range (L2-local)
__global__ void csr_build_kernel(const int* __restrict__ bpack, const int* __restrict__ boff,
                                 int* __restrict__ row_start, int* __restrict__ csr,
                                 int N, int NB) {
    __shared__ int lcnt[128];
    __shared__ int lex[128];
    int b = blockIdx.x;
    int tid = threadIdx.x;   // 256
    int beg = boff[b], end = boff[b + 1];
    if (tid < 128) lcnt[tid] = 0;
    __syncthreads();
    for (int i = beg + tid; i < end; i += 256) atomicAdd(&lcnt[bpack[i] >> 24], 1);
    __syncthreads();
    if (tid < 128) lex[tid] = lcnt[tid];
    __syncthreads();
    for (int off = 1; off < 128; off <<= 1) {
        int v = (tid < 128 && tid >= off) ? lex[tid - off] : 0;
        __syncthreads();
        if (tid < 128) lex[tid] += v;
        __syncthreads();
    }
    int nodeBase = b << 7;
    if (tid < 128) {
        int node = nodeBase + tid;
        if (node < N) row_start[node] = beg + (tid ? lex[tid - 1] : 0);
    }
    if (b == NB - 1 && tid == 0) row_start[N] = end;
    __syncthreads();
    if (tid < 128) lcnt[tid] = (tid ? lex[tid - 1] : 0);   // exclusive prefix as cursor
    __syncthreads();
    for (int i = beg + tid; i < end; i += 256) {
        int v = bpack[i];
        int ld = v >> 24, src = v & 0xFFFFFF;
        int pos = atomicAdd(&lcnt[ld], 1);
        csr[beg + pos] = src;
    }
}

// ================= gather: 16 lanes/node, float4/lane =================
__global__ void gather64_kernel(const float* __restrict__ x, const int* __restrict__ rs,
                                const int* __restrict__ csr, float* __restrict__ aggr, int N) {
    int lane = threadIdx.x & 63;
    int l4 = lane & 15;
    int wave = (blockIdx.x * blockDim.x + threadIdx.x) >> 6;
    int n = wave * 4 + (lane >> 4);
    if (n >= N) return;
    int beg = rs[n], end = rs[n + 1];
    float ax = 0, ay = 0, az = 0, aw = 0;
    for (int base = beg; base < end; base += 16) {
        int cnt = end - base; if (cnt > 16) cnt = 16;
        int e = (l4 < cnt) ? csr[base + l4] : 0;
        for (int j = 0; j < cnt; j++) {
            int s = __shfl(e, j, 16);
            const float4 v = *reinterpret_cast<const float4*>(x + (size_t)s * 64 + l4 * 4);
            ax += v.x; ay += v.y; az += v.z; aw += v.w;
        }
    }
    float4 o = {ax, ay, az, aw};
    *reinterpret_cast<float4*>(aggr + (size_t)n * 64 + l4 * 4) = o;
}

__global__ void gather16_kernel(const float* __restrict__ x, const int* __restrict__ rs,
                                const int* __restrict__ csr, float* __restrict__ aggr, int N) {
    int lane = threadIdx.x & 63;
    int l4 = lane & 3;
    int wave = (blockIdx.x * blockDim.x + threadIdx.x) >> 6;
    int n = wave * 16 + (lane >> 2);
    if (n >= N) return;
    int beg = rs[n], end = rs[n + 1];
    float ax = 0, ay = 0, az = 0, aw = 0;
    for (int base = beg; base < end; base += 4) {
        int cnt = end - base; if (cnt > 4) cnt = 4;
        int e = (l4 < cnt) ? csr[base + l4] : 0;
        for (int j = 0; j < cnt; j++) {
            int s = __shfl(e, j, 4);
            const float4 v = *reinterpret_cast<const float4*>(x + (size_t)s * 16 + l4 * 4);
            ax += v.x; ay += v.y; az += v.z; aw += v.w;
        }
    }
    float4 o = {ax, ay, az, aw};
    *reinterpret_cast<float4*>(aggr + (size_t)n * 16 + l4 * 4) = o;
}

// ======== fused MLP: 4x4 register tile, k-major LDS, prep (BN fold) inlined ========
// AFF: Wa_eff = diag(a)*Wa with a,c from prev layer stats; bias += (1+eps+deg)*(c@Wa)
template <int DIN, bool AFF>
__launch_bounds__(256)
__global__ void fused_mlp_kernel(const float* __restrict__ xin, const float* __restrict__ aggr,
                                 const int* __restrict__ rs,
                                 const float* __restrict__ Wa, const float* __restrict__ ba,
                                 const float* __restrict__ Wb, const float* __restrict__ bb,
                                 const float* __restrict__ epsp,
                                 const float* __restrict__ statsPrev,
                                 const float* __restrict__ gPrev, const float* __restrict__ bePrev,
                                 float* __restrict__ hout, float* __restrict__ stats, int N) {
    __shared__ float Wa_s[DIN * 64];
    __shared__ float Wb_s[64 * 64];
    __shared__ float zts[64 * 68];
    __shared__ float statS[128];
    __shared__ float degS[64];
    __shared__ float aS[64], cS[64], uS[64];

    const int tid = threadIdx.x;
    const int tc = tid & 15;
    const int tn = tid >> 4;

    if (AFF) {
        if (tid < 64) {
            float invN = 1.0f / (float)N;
            float mu = statsPrev[tid] * invN;
            float var = statsPrev[64 + tid] * invN - mu * mu;
            float inv = rsqrtf(var + 1e-5f);
            float a = gPrev[tid] * inv;
            aS[tid] = a;
            cS[tid] = bePrev[tid] - mu * a;
        }
        __syncthreads();
        for (int i = tid; i < DIN * 64; i += 256) Wa_s[i] = aS[i >> 6] * Wa[i];
        if (tid < 64) {
            float s = 0.0f;
            for (int k = 0; k < 64; k++) s = fmaf(cS[k], Wa[k * 64 + tid], s);
            uS[tid] = s;
        }
    } else {
        for (int i = tid; i < DIN * 64; i += 256) Wa_s[i] = Wa[i];
    }
    for (int i = tid; i < 64 * 64; i += 256) Wb_s[i] = Wb[i];
    if (tid < 128) statS[tid] = 0.0f;
    const float e1 = 1.0f + epsp[0];
    __syncthreads();

    float4 t4;
    t4 = *(const float4*)&ba[tc * 4];
    const float bav[4] = {t4.x, t4.y, t4.z, t4.w};
    t4 = *(const float4*)&bb[tc * 4];
    const float bbv[4] = {t4.x, t4.y, t4.z, t4.w};
    float uv[4] = {0, 0, 0, 0};
    if (AFF) { uv[0] = uS[tc * 4]; uv[1] = uS[tc * 4 + 1]; uv[2] = uS[tc * 4 + 2]; uv[3] = uS[tc * 4 + 3]; }

    float sv[4] = {0, 0, 0, 0}, qv[4] = {0, 0, 0, 0};

    const int ITER = 2;
    int blockBase = blockIdx.x * (64 * ITER);
    for (int it = 0; it < ITER; ++it) {
        int gbase = blockBase + it * 64;
        float zr[4][4];
        if (DIN == 64) {
#pragma unroll
            for (int i = 0; i < 4; ++i) {
                int node = gbase + tn * 4 + i;
                float4 xv = {0, 0, 0, 0}, av = {0, 0, 0, 0};
                if (node < N) {
                    xv = *(const float4*)&xin[(size_t)node * 64 + tc * 4];
                    av = *(const float4*)&aggr[(size_t)node * 64 + tc * 4];
                }
                zr[i][0] = fmaf(e1, xv.x, av.x);
                zr[i][1] = fmaf(e1, xv.y, av.y);
                zr[i][2] = fmaf(e1, xv.z, av.z);
                zr[i][3] = fmaf(e1, xv.w, av.w);
            }
        } else {
            int node = gbase + tn * 4 + (tc >> 2);
            float4 xv = {0, 0, 0, 0}, av = {0, 0, 0, 0};
            if (node < N) {
                xv = *(const float4*)&xin[(size_t)node * 16 + (tc & 3) * 4];
                av = *(const float4*)&aggr[(size_t)node * 16 + (tc & 3) * 4];
            }
            zr[0][0] = fmaf(e1, xv.x, av.x);
            zr[0][1] = fmaf(e1, xv.y, av.y);
            zr[0][2] = fmaf(e1, xv.z, av.z);
            zr[0][3] = fmaf(e1, xv.w, av.w);
        }
        float dg[4];
        if (AFF && tid < 64) {
            int node = gbase + tid;
            degS[tid] = (node < N) ? (float)(rs[node + 1] - rs[node]) : 0.0f;
        }
        __syncthreads();                       // bar0
        if (DIN == 64) {
#pragma unroll
            for (int j = 0; j < 4; ++j) {
                float4 w = {zr[0][j], zr[1][j], zr[2][j], zr[3][j]};
                *(float4*)&zts[(tc * 4 + j) * 68 + tn * 4] = w;
            }
        } else {
#pragma unroll
            for (int j = 0; j < 4; ++j)
                zts[((tc & 3) * 4 + j) * 68 + tn * 4 + (tc >> 2)] = zr[0][j];
        }
        __syncthreads();                       // bar1
        if (AFF) {
#pragma unroll
            for (int i = 0; i < 4; ++i) dg[i] = e1 + degS[tn * 4 + i];
        }
        float ac[4][4];
#pragma unroll
        for (int i = 0; i < 4; ++i)
#pragma unroll
            for (int j = 0; j < 4; ++j)
                ac[i][j] = AFF ? fmaf(dg[i], uv[j], bav[j]) : bav[j];
#pragma unroll 8
        for (int k = 0; k < DIN; ++k) {
            float4 zv = *(const float4*)&zts[k * 68 + tn * 4];
            float4 wv = *(const float4*)&Wa_s[k * 64 + tc * 4];
            const float zf[4] = {zv.x, zv.y, zv.z, zv.w};
            const float wf[4] = {wv.x, wv.y, wv.z, wv.w};
#pragma unroll
            for (int i = 0; i < 4; ++i)
#pragma unroll
                for (int j = 0; j < 4; ++j)
                    ac[i][j] = fmaf(zf[i], wf[j], ac[i][j]);
        }
#pragma unroll
        for (int i = 0; i < 4; ++i)
#pragma unroll
            for (int j = 0; j < 4; ++j)
                ac[i][j] = fmaxf(ac[i][j], 0.0f);
        __syncthreads();                       // bar2
#pragma unroll
        for (int j = 0; j < 4; ++j) {
            float4 w = {ac[0][j], ac[1][j], ac[2][j], ac[3][j]};
            *(float4*)&zts[(tc * 4 + j) * 68 + tn * 4] = w;
        }
        __syncthreads();                       // bar3
        float hc[4][4];
#pragma unroll
        for (int i = 0; i < 4; ++i)
#pragma unroll
            for (int j = 0; j < 4; ++j)
                hc[i][j] = bbv[j];
#pragma unroll 8
        for (int k = 0; k < 64; ++k) {
            float4 tv = *(const float4*)&zts[k * 68 + tn * 4];
            float4 wv = *(const float4*)&Wb_s[k * 64 + tc * 4];
            const float tf[4] = {tv.x, tv.y, tv.z, tv.w};
            const float wf[4] = {wv.x, wv.y, wv.z, wv.w};
#pragma unroll
            for (int i = 0; i < 4; ++i)
#pragma unroll
                for (int j = 0; j < 4; ++j)
                    hc[i][j] = fmaf(tf[i], wf[j], hc[i][j]);
        }
#pragma unroll
        for (int i = 0; i < 4; ++i) {
            int node = gbase + tn * 4 + i;
            if (node < N) {
                float4 o;
                o.x = fmaxf(hc[i][0], 0.0f); o.y = fmaxf(hc[i][1], 0.0f);
                o.z = fmaxf(hc[i][2], 0.0f); o.w = fmaxf(hc[i][3], 0.0f);
                *(float4*)&hout[(size_t)node * 64 + tc * 4] = o;
                sv[0] += o.x; sv[1] += o.y; sv[2] += o.z; sv[3] += o.w;
                qv[0] += o.x * o.x; qv[1] += o.y * o.y; qv[2] += o.z * o.z; qv[3] += o.w * o.w;
            }
        }
    }
#pragma unroll
    for (int off = 16; off < 64; off <<= 1) {
#pragma unroll
        for (int j = 0; j < 4; ++j) {
            sv[j] += __shfl_xor(sv[j], off);
            qv[j] += __shfl_xor(qv[j], off);
        }
    }
    if ((tid & 63) < 16) {
#pragma unroll
        for (int j = 0; j < 4; ++j) {
            atomicAdd(&statS[tc * 4 + j], sv[j]);
            atomicAdd(&statS[64 + tc * 4 + j], qv[j]);
        }
    }
    __syncthreads();
    if (tid < 128) unsafeAtomicAdd(&stats[tid], statS[tid]);
}

// ================= segmented pool (batch sorted) =================
__global__ void pool_seg_kernel(const float* __restrict__ h, const int* __restrict__ batch,
                                float* __restrict__ pool, float* __restrict__ cnt, int N) {
    int lane = threadIdx.x & 63;
    int wave = (blockIdx.x * blockDim.x + threadIdx.x) >> 6;
    int base = wave * 16;
    if (base >= N) return;
    int end = base + 16; if (end > N) end = N;
    int cur = batch[base];
    float acc = 0.0f;
    int run = 0;
    for (int n = base; n < end; n++) {
        int gid = batch[n];
        if (gid != cur) {
            unsafeAtomicAdd(&pool[(size_t)cur * 64 + lane], acc);
            if (lane == 0) unsafeAtomicAdd(&cnt[cur], (float)run);
            acc = 0.0f; run = 0; cur = gid;
        }
        acc += h[(size_t)n * 64 + lane];
        run++;
    }
    unsafeAtomicAdd(&pool[(size_t)cur * 64 + lane], acc);
    if (lane == 0) unsafeAtomicAdd(&cnt[cur], (float)run);
}

// ================= readout (applies BN3 affine to pooled mean) =================
__global__ void readout_kernel(const float* __restrict__ pool, const float* __restrict__ cnt,
                               const float* __restrict__ stats, const float* __restrict__ g3,
                               const float* __restrict__ be3,
                               const float* __restrict__ Wf1, const float* __restrict__ bf1,
                               const float* __restrict__ Wf2, const float* __restrict__ bf2,
                               float* __restrict__ out, int N) {
    int gb = blockIdx.x;
    int t = threadIdx.x;  // 64 threads
    float invN = 1.0f / (float)N;
    float mu = stats[t] * invN;
    float var = stats[64 + t] * invN - mu * mu;
    float inv = rsqrtf(var + 1e-5f);
    float a = g3[t] * inv;
    float c = be3[t] - mu * a;
    float cn = cnt[gb];
    float p = (cn > 0.0f) ? (a * (pool[(size_t)gb * 64 + t] / cn) + c) : 0.0f;
    float o = 0.0f;
#pragma unroll
    for (int j = 0; j < 10; j++) {
        float part = p * Wf1[t * 10 + j];
#pragma unroll
        for (int off = 32; off > 0; off >>= 1) part += __shfl_down(part, off);
        float z = fmaxf(part + bf1[j], 0.0f);   // valid on lane 0 only
        o = fmaf(z, Wf2[j], o);
    }
    if (t == 0) out[gb] = o + bf2[0];
}

extern "C" void kernel_launch(void* const* d_in, const int* in_sizes, int n_in,
                              void* d_out, int out_size, void* d_ws, size_t ws_size,
                              hipStream_t stream) {
    const float* x      = (const float*)d_in[0];
    const int*   ei     = (const int*)d_in[1];
    const int*   batch  = (const int*)d_in[2];
    const float* W1a = (const float*)d_in[3];  const float* b1a = (const float*)d_in[4];
    const float* W1b = (const float*)d_in[5];  const float* b1b = (const float*)d_in[6];
    const float* e1  = (const float*)d_in[7];  const float* g1  = (const float*)d_in[8];
    const float* be1 = (const float*)d_in[9];
    const float* W2a = (const float*)d_in[10]; const float* b2a = (const float*)d_in[11];
    const float* W2b = (const float*)d_in[12]; const float* b2b = (const float*)d_in[13];
    const float* e2  = (const float*)d_in[14]; const float* g2  = (const float*)d_in[15];
    const float* be2 = (const float*)d_in[16];
    const float* W3a = (const float*)d_in[17]; const float* b3a = (const float*)d_in[18];
    const float* W3b = (const float*)d_in[19]; const float* b3b = (const float*)d_in[20];
    const float* e3  = (const float*)d_in[21]; const float* g3  = (const float*)d_in[22];
    const float* be3 = (const float*)d_in[23];
    const float* Wf1 = (const float*)d_in[24]; const float* bf1 = (const float*)d_in[25];
    const float* Wf2 = (const float*)d_in[26]; const float* bf2 = (const float*)d_in[27];

    const int N = in_sizes[2];
    const int E = in_sizes[1] / 2;
    const int G = out_size;
    const int NB = (N + 127) >> 7;             // buckets of 128 nodes (NB <= 1024)

    // ---------- workspace layout (all starts 16B-aligned) ----------
    int* csr       = (int*)d_ws;               // E
    int* row_start = csr + E;                  // N+64
    int* bpack     = row_start + N + 64;       // E
    int* boff      = bpack + E;                // NB+1 (pad 1040)
    // --- contiguous zero-init region ---
    int* bcnt      = boff + 1040;              // 1024
    int* bcur      = bcnt + 1024;              // 1024
    float* stats   = (float*)(bcur + 1024);    // 3*128
    float* pool    = stats + 384;              // G*64
    float* cnt     = pool + (size_t)G * HD;    // G
    // --- end zero region ---
    float* aggr    = cnt + G;                  // N*64
    size_t NH = (size_t)N * HD;
    float* hA      = aggr + NH;                // N*64
    float* hB      = hA + NH;                  // N*64

    const int TB = 256;
    int fusedGrid = (N + 127) / 128;
    size_t zeroBytes = (size_t)(2048) * 4 + (size_t)(384 + (size_t)G * HD + G) * 4;

    // ---------- CSR build (two-level bucket sort) ----------
    hipMemsetAsync(bcnt, 0, zeroBytes, stream);
    bucket_hist_kernel<<<(E + TB - 1) / TB, TB, 0, stream>>>(ei, bcnt, E);
    bucket_scan_kernel<<<1, 1024, 0, stream>>>(bcnt, boff, NB);
    bucket_scatter_kernel<<<(E + TB - 1) / TB, TB, 0, stream>>>(ei, boff, bcur, bpack, E);
    csr_build_kernel<<<NB, TB, 0, stream>>>(bpack, boff, row_start, csr, N, NB);

    // ---------- layer 1: x(16) -> hA, stats1 ----------
    gather16_kernel<<<((N + 15) / 16 * 64 + TB - 1) / TB, TB, 0, stream>>>(x, row_start, csr, aggr, N);
    fused_mlp_kernel<16, false><<<fusedGrid, TB, 0, stream>>>(
        x, aggr, row_start, W1a, b1a, W1b, b1b, e1, nullptr, nullptr, nullptr, hA, stats, N);

    // ---------- layer 2: hA -> hB, BN1 folded ----------
    gather64_kernel<<<((N + 3) / 4 * 64 + TB - 1) / TB, TB, 0, stream>>>(hA, row_start, csr, aggr, N);
    fused_mlp_kernel<64, true><<<fusedGrid, TB, 0, stream>>>(
        hA, aggr, row_start, W2a, b2a, W2b, b2b, e2, stats, g1, be1, hB, stats + 128, N);

    // ---------- layer 3: hB -> hA, BN2 folded ----------
    gather64_kernel<<<((N + 3) / 4 * 64 + TB - 1) / TB, TB, 0, stream>>>(hB, row_start, csr, aggr, N);
    fused_mlp_kernel<64, true><<<fusedGrid, TB, 0, stream>>>(
        hB, aggr, row_start, W3a, b3a, W3b, b3b, e3, stats + 128, g2, be2, hA, stats + 256, N);

    // ---------- pool raw h3 (BN3 affine applied in readout) ----------
    int poolWaves = (N + 15) / 16;
    pool_seg_kernel<<<(poolWaves * 64 + TB - 1) / TB, TB, 0, stream>>>(hA, batch, pool, cnt, N);
    readout_kernel<<<G, 64, 0, stream>>>(pool, cnt, stats + 256, g3, be3,
                                         Wf1, bf1, Wf2, bf2, (float*)d_out, N);
}

// Round 7
// 533.927 us; speedup vs baseline: 1.8451x; 1.8451x over previous
//
#include <hip/hip_runtime.h>
#include <hip/hip_bf16.h>

// GIN net, round 7: revert CSR build to r4 counting sort (r6 bucket build hit
// atomic-contention wall: 1.2M atomics on 782 addrs = 284us). scanwrite now also
// seeds cursor=row_start (drops memset + row_start read in fill). Gathers get
// 4-wide ILP unroll (4 independent float4 accumulators -> 4 loads in flight).

#define HD 64

// ================= CSR build: counting sort by dst =================
__global__ void degree_kernel(const int* __restrict__ ei, int* __restrict__ deg, int E) {
    int e = blockIdx.x * blockDim.x + threadIdx.x;
    if (e >= E) return;
    atomicAdd(&deg[ei[E + e]], 1);
}

__global__ void blocksum_kernel(const int* __restrict__ deg, int* __restrict__ bsum, int N) {
    __shared__ int wsum[4];
    int base = blockIdx.x * 1024 + threadIdx.x * 4;
    int s = 0;
#pragma unroll
    for (int k = 0; k < 4; k++) { int i = base + k; if (i < N) s += deg[i]; }
    for (int off = 1; off < 64; off <<= 1) s += __shfl_xor(s, off);
    if ((threadIdx.x & 63) == 0) wsum[threadIdx.x >> 6] = s;
    __syncthreads();
    if (threadIdx.x == 0) bsum[blockIdx.x] = wsum[0] + wsum[1] + wsum[2] + wsum[3];
}

__global__ void scansums_kernel(const int* __restrict__ bsum, int* __restrict__ boff, int nb) {
    if (threadIdx.x != 0 || blockIdx.x != 0) return;
    int acc = 0;
    for (int i = 0; i < nb; i++) { boff[i] = acc; acc += bsum[i]; }
}

// writes row_start (inclusive at i+1) AND cursor[i] = exclusive prefix (= row_start[i])
__global__ void scanwrite_kernel(const int* __restrict__ deg, const int* __restrict__ boff,
                                 int* __restrict__ row_start, int* __restrict__ cursor, int N) {
    __shared__ int wsumS[4];
    int lane = threadIdx.x & 63, wid = threadIdx.x >> 6;
    int base = blockIdx.x * 1024 + threadIdx.x * 4;
    int v0 = 0, v1 = 0, v2 = 0, v3 = 0;
    if (base + 0 < N) v0 = deg[base + 0];
    if (base + 1 < N) v1 = deg[base + 1];
    if (base + 2 < N) v2 = deg[base + 2];
    if (base + 3 < N) v3 = deg[base + 3];
    int st = v0 + v1 + v2 + v3;
    int v = st;
    for (int off = 1; off < 64; off <<= 1) { int u = __shfl_up(v, off); if (lane >= off) v += u; }
    if (lane == 63) wsumS[wid] = v;
    __syncthreads();
    int woff = 0;
    for (int w = 0; w < wid; w++) woff += wsumS[w];
    int r = boff[blockIdx.x] + woff + (v - st);   // exclusive prefix
    if (blockIdx.x == 0 && threadIdx.x == 0) row_start[0] = 0;
    if (base + 0 < N) { cursor[base + 0] = r; r += v0; row_start[base + 1] = r; }
    if (base + 1 < N) { cursor[base + 1] = r; r += v1; row_start[base + 2] = r; }
    if (base + 2 < N) { cursor[base + 2] = r; r += v2; row_start[base + 3] = r; }
    if (base + 3 < N) { cursor[base + 3] = r; r += v3; row_start[base + 4] = r; }
}

__global__ void fill_kernel(const int* __restrict__ ei, int* __restrict__ cursor,
                            int* __restrict__ csr, int E) {
    int e = blockIdx.x * blockDim.x + threadIdx.x;
    if (e >= E) return;
    int pos = atomicAdd(&cursor[ei[E + e]], 1);
    csr[pos] = ei[e];
}

// ======== gather: 16 lanes/node, float4/lane, 4-wide ILP unroll ========
__global__ void gather64_kernel(const float* __restrict__ x, const int* __restrict__ rs,
                                const int* __restrict__ csr, float* __restrict__ aggr, int N) {
    int lane = threadIdx.x & 63;
    int l4 = lane & 15;
    int wave = (blockIdx.x * blockDim.x + threadIdx.x) >> 6;
    int n = wave * 4 + (lane >> 4);
    if (n >= N) return;
    int beg = rs[n], end = rs[n + 1];
    const float* xb = x + (size_t)l4 * 4;
    float a0x = 0, a0y = 0, a0z = 0, a0w = 0;
    float a1x = 0, a1y = 0, a1z = 0, a1w = 0;
    float a2x = 0, a2y = 0, a2z = 0, a2w = 0;
    float a3x = 0, a3y = 0, a3z = 0, a3w = 0;
    for (int base = beg; base < end; base += 16) {
        int cnt = end - base; if (cnt > 16) cnt = 16;
        int e = (l4 < cnt) ? csr[base + l4] : 0;
        int j = 0;
        for (; j + 4 <= cnt; j += 4) {
            int s0 = __shfl(e, j + 0, 16);
            int s1 = __shfl(e, j + 1, 16);
            int s2 = __shfl(e, j + 2, 16);
            int s3 = __shfl(e, j + 3, 16);
            float4 v0 = *(const float4*)(xb + (size_t)s0 * 64);
            float4 v1 = *(const float4*)(xb + (size_t)s1 * 64);
            float4 v2 = *(const float4*)(xb + (size_t)s2 * 64);
            float4 v3 = *(const float4*)(xb + (size_t)s3 * 64);
            a0x += v0.x; a0y += v0.y; a0z += v0.z; a0w += v0.w;
            a1x += v1.x; a1y += v1.y; a1z += v1.z; a1w += v1.w;
            a2x += v2.x; a2y += v2.y; a2z += v2.z; a2w += v2.w;
            a3x += v3.x; a3y += v3.y; a3z += v3.z; a3w += v3.w;
        }
        for (; j < cnt; j++) {
            int s = __shfl(e, j, 16);
            float4 v = *(const float4*)(xb + (size_t)s * 64);
            a0x += v.x; a0y += v.y; a0z += v.z; a0w += v.w;
        }
    }
    float4 o;
    o.x = (a0x + a1x) + (a2x + a3x);
    o.y = (a0y + a1y) + (a2y + a3y);
    o.z = (a0z + a1z) + (a2z + a3z);
    o.w = (a0w + a1w) + (a2w + a3w);
    *reinterpret_cast<float4*>(aggr + (size_t)n * 64 + l4 * 4) = o;
}

__global__ void gather16_kernel(const float* __restrict__ x, const int* __restrict__ rs,
                                const int* __restrict__ csr, float* __restrict__ aggr, int N) {
    int lane = threadIdx.x & 63;
    int l4 = lane & 3;
    int wave = (blockIdx.x * blockDim.x + threadIdx.x) >> 6;
    int n = wave * 16 + (lane >> 2);
    if (n >= N) return;
    int beg = rs[n], end = rs[n + 1];
    const float* xb = x + (size_t)l4 * 4;
    float a0x = 0, a0y = 0, a0z = 0, a0w = 0;
    float a1x = 0, a1y = 0, a1z = 0, a1w = 0;
    float a2x = 0, a2y = 0, a2z = 0, a2w = 0;
    float a3x = 0, a3y = 0, a3z = 0, a3w = 0;
    for (int base = beg; base < end; base += 4) {
        int cnt = end - base; if (cnt > 4) cnt = 4;
        int e = (l4 < cnt) ? csr[base + l4] : 0;
        if (cnt == 4) {
            int s0 = __shfl(e, 0, 4);
            int s1 = __shfl(e, 1, 4);
            int s2 = __shfl(e, 2, 4);
            int s3 = __shfl(e, 3, 4);
            float4 v0 = *(const float4*)(xb + (size_t)s0 * 16);
            float4 v1 = *(const float4*)(xb + (size_t)s1 * 16);
            float4 v2 = *(const float4*)(xb + (size_t)s2 * 16);
            float4 v3 = *(const float4*)(xb + (size_t)s3 * 16);
            a0x += v0.x; a0y += v0.y; a0z += v0.z; a0w += v0.w;
            a1x += v1.x; a1y += v1.y; a1z += v1.z; a1w += v1.w;
            a2x += v2.x; a2y += v2.y; a2z += v2.z; a2w += v2.w;
            a3x += v3.x; a3y += v3.y; a3z += v3.z; a3w += v3.w;
        } else {
            for (int j = 0; j < cnt; j++) {
                int s = __shfl(e, j, 4);
                float4 v = *(const float4*)(xb + (size_t)s * 16);
                a0x += v.x; a0y += v.y; a0z += v.z; a0w += v.w;
            }
        }
    }
    float4 o;
    o.x = (a0x + a1x) + (a2x + a3x);
    o.y = (a0y + a1y) + (a2y + a3y);
    o.z = (a0z + a1z) + (a2z + a3z);
    o.w = (a0w + a1w) + (a2w + a3w);
    *reinterpret_cast<float4*>(aggr + (size_t)n * 16 + l4 * 4) = o;
}

// ======== fused MLP: 4x4 register tile, k-major LDS, prep (BN fold) inlined ========
template <int DIN, bool AFF>
__launch_bounds__(256)
__global__ void fused_mlp_kernel(const float* __restrict__ xin, const float* __restrict__ aggr,
                                 const int* __restrict__ rs,
                                 const float* __restrict__ Wa, const float* __restrict__ ba,
                                 const float* __restrict__ Wb, const float* __restrict__ bb,
                                 const float* __restrict__ epsp,
                                 const float* __restrict__ statsPrev,
                                 const float* __restrict__ gPrev, const float* __restrict__ bePrev,
                                 float* __restrict__ hout, float* __restrict__ stats, int N) {
    __shared__ float Wa_s[DIN * 64];
    __shared__ float Wb_s[64 * 64];
    __shared__ float zts[64 * 68];
    __shared__ float statS[128];
    __shared__ float degS[64];
    __shared__ float aS[64], cS[64], uS[64];

    const int tid = threadIdx.x;
    const int tc = tid & 15;
    const int tn = tid >> 4;

    if (AFF) {
        if (tid < 64) {
            float invN = 1.0f / (float)N;
            float mu = statsPrev[tid] * invN;
            float var = statsPrev[64 + tid] * invN - mu * mu;
            float inv = rsqrtf(var + 1e-5f);
            float a = gPrev[tid] * inv;
            aS[tid] = a;
            cS[tid] = bePrev[tid] - mu * a;
        }
        __syncthreads();
        for (int i = tid; i < DIN * 64; i += 256) Wa_s[i] = aS[i >> 6] * Wa[i];
        if (tid < 64) {
            float s = 0.0f;
            for (int k = 0; k < 64; k++) s = fmaf(cS[k], Wa[k * 64 + tid], s);
            uS[tid] = s;
        }
    } else {
        for (int i = tid; i < DIN * 64; i += 256) Wa_s[i] = Wa[i];
    }
    for (int i = tid; i < 64 * 64; i += 256) Wb_s[i] = Wb[i];
    if (tid < 128) statS[tid] = 0.0f;
    const float e1 = 1.0f + epsp[0];
    __syncthreads();

    float4 t4;
    t4 = *(const float4*)&ba[tc * 4];
    const float bav[4] = {t4.x, t4.y, t4.z, t4.w};
    t4 = *(const float4*)&bb[tc * 4];
    const float bbv[4] = {t4.x, t4.y, t4.z, t4.w};
    float uv[4] = {0, 0, 0, 0};
    if (AFF) { uv[0] = uS[tc * 4]; uv[1] = uS[tc * 4 + 1]; uv[2] = uS[tc * 4 + 2]; uv[3] = uS[tc * 4 + 3]; }

    float sv[4] = {0, 0, 0, 0}, qv[4] = {0, 0, 0, 0};

    const int ITER = 2;
    int blockBase = blockIdx.x * (64 * ITER);
    for (int it = 0; it < ITER; ++it) {
        int gbase = blockBase + it * 64;
        float zr[4][4];
        if (DIN == 64) {
#pragma unroll
            for (int i = 0; i < 4; ++i) {
                int node = gbase + tn * 4 + i;
                float4 xv = {0, 0, 0, 0}, av = {0, 0, 0, 0};
                if (node < N) {
                    xv = *(const float4*)&xin[(size_t)node * 64 + tc * 4];
                    av = *(const float4*)&aggr[(size_t)node * 64 + tc * 4];
                }
                zr[i][0] = fmaf(e1, xv.x, av.x);
                zr[i][1] = fmaf(e1, xv.y, av.y);
                zr[i][2] = fmaf(e1, xv.z, av.z);
                zr[i][3] = fmaf(e1, xv.w, av.w);
            }
        } else {
            int node = gbase + tn * 4 + (tc >> 2);
            float4 xv = {0, 0, 0, 0}, av = {0, 0, 0, 0};
            if (node < N) {
                xv = *(const float4*)&xin[(size_t)node * 16 + (tc & 3) * 4];
                av = *(const float4*)&aggr[(size_t)node * 16 + (tc & 3) * 4];
            }
            zr[0][0] = fmaf(e1, xv.x, av.x);
            zr[0][1] = fmaf(e1, xv.y, av.y);
            zr[0][2] = fmaf(e1, xv.z, av.z);
            zr[0][3] = fmaf(e1, xv.w, av.w);
        }
        float dg[4];
        if (AFF && tid < 64) {
            int node = gbase + tid;
            degS[tid] = (node < N) ? (float)(rs[node + 1] - rs[node]) : 0.0f;
        }
        __syncthreads();                       // bar0
        if (DIN == 64) {
#pragma unroll
            for (int j = 0; j < 4; ++j) {
                float4 w = {zr[0][j], zr[1][j], zr[2][j], zr[3][j]};
                *(float4*)&zts[(tc * 4 + j) * 68 + tn * 4] = w;
            }
        } else {
#pragma unroll
            for (int j = 0; j < 4; ++j)
                zts[((tc & 3) * 4 + j) * 68 + tn * 4 + (tc >> 2)] = zr[0][j];
        }
        __syncthreads();                       // bar1
        if (AFF) {
#pragma unroll
            for (int i = 0; i < 4; ++i) dg[i] = e1 + degS[tn * 4 + i];
        }
        float ac[4][4];
#pragma unroll
        for (int i = 0; i < 4; ++i)
#pragma unroll
            for (int j = 0; j < 4; ++j)
                ac[i][j] = AFF ? fmaf(dg[i], uv[j], bav[j]) : bav[j];
#pragma unroll 8
        for (int k = 0; k < DIN; ++k) {
            float4 zv = *(const float4*)&zts[k * 68 + tn * 4];
            float4 wv = *(const float4*)&Wa_s[k * 64 + tc * 4];
            const float zf[4] = {zv.x, zv.y, zv.z, zv.w};
            const float wf[4] = {wv.x, wv.y, wv.z, wv.w};
#pragma unroll
            for (int i = 0; i < 4; ++i)
#pragma unroll
                for (int j = 0; j < 4; ++j)
                    ac[i][j] = fmaf(zf[i], wf[j], ac[i][j]);
        }
#pragma unroll
        for (int i = 0; i < 4; ++i)
#pragma unroll
            for (int j = 0; j < 4; ++j)
                ac[i][j] = fmaxf(ac[i][j], 0.0f);
        __syncthreads();                       // bar2
#pragma unroll
        for (int j = 0; j < 4; ++j) {
            float4 w = {ac[0][j], ac[1][j], ac[2][j], ac[3][j]};
            *(float4*)&zts[(tc * 4 + j) * 68 + tn * 4] = w;
        }
        __syncthreads();                       // bar3
        float hc[4][4];
#pragma unroll
        for (int i = 0; i < 4; ++i)
#pragma unroll
            for (int j = 0; j < 4; ++j)
                hc[i][j] = bbv[j];
#pragma unroll 8
        for (int k = 0; k < 64; ++k) {
            float4 tv = *(const float4*)&zts[k * 68 + tn * 4];
            float4 wv = *(const float4*)&Wb_s[k * 64 + tc * 4];
            const float tf[4] = {tv.x, tv.y, tv.z, tv.w};
            const float wf[4] = {wv.x, wv.y, wv.z, wv.w};
#pragma unroll
            for (int i = 0; i < 4; ++i)
#pragma unroll
                for (int j = 0; j < 4; ++j)
                    hc[i][j] = fmaf(tf[i], wf[j], hc[i][j]);
        }
#pragma unroll
        for (int i = 0; i < 4; ++i) {
            int node = gbase + tn * 4 + i;
            if (node < N) {
                float4 o;
                o.x = fmaxf(hc[i][0], 0.0f); o.y = fmaxf(hc[i][1], 0.0f);
                o.z = fmaxf(hc[i][2], 0.0f); o.w = fmaxf(hc[i][3], 0.0f);
                *(float4*)&hout[(size_t)node * 64 + tc * 4] = o;
                sv[0] += o.x; sv[1] += o.y; sv[2] += o.z; sv[3] += o.w;
                qv[0] += o.x * o.x; qv[1] += o.y * o.y; qv[2] += o.z * o.z; qv[3] += o.w * o.w;
            }
        }
    }
#pragma unroll
    for (int off = 16; off < 64; off <<= 1) {
#pragma unroll
        for (int j = 0; j < 4; ++j) {
            sv[j] += __shfl_xor(sv[j], off);
            qv[j] += __shfl_xor(qv[j], off);
        }
    }
    if ((tid & 63) < 16) {
#pragma unroll
        for (int j = 0; j < 4; ++j) {
            atomicAdd(&statS[tc * 4 + j], sv[j]);
            atomicAdd(&statS[64 + tc * 4 + j], qv[j]);
        }
    }
    __syncthreads();
    if (tid < 128) unsafeAtomicAdd(&stats[tid], statS[tid]);
}

// ================= segmented pool (batch sorted) =================
__global__ void pool_seg_kernel(const float* __restrict__ h, const int* __restrict__ batch,
                                float* __restrict__ pool, float* __restrict__ cnt, int N) {
    int lane = threadIdx.x & 63;
    int wave = (blockIdx.x * blockDim.x + threadIdx.x) >> 6;
    int base = wave * 16;
    if (base >= N) return;
    int end = base + 16; if (end > N) end = N;
    int cur = batch[base];
    float acc = 0.0f;
    int run = 0;
    for (int n = base; n < end; n++) {
        int gid = batch[n];
        if (gid != cur) {
            unsafeAtomicAdd(&pool[(size_t)cur * 64 + lane], acc);
            if (lane == 0) unsafeAtomicAdd(&cnt[cur], (float)run);
            acc = 0.0f; run = 0; cur = gid;
        }
        acc += h[(size_t)n * 64 + lane];
        run++;
    }
    unsafeAtomicAdd(&pool[(size_t)cur * 64 + lane], acc);
    if (lane == 0) unsafeAtomicAdd(&cnt[cur], (float)run);
}

// ================= readout (applies BN3 affine to pooled mean) =================
__global__ void readout_kernel(const float* __restrict__ pool, const float* __restrict__ cnt,
                               const float* __restrict__ stats, const float* __restrict__ g3,
                               const float* __restrict__ be3,
                               const float* __restrict__ Wf1, const float* __restrict__ bf1,
                               const float* __restrict__ Wf2, const float* __restrict__ bf2,
                               float* __restrict__ out, int N) {
    int gb = blockIdx.x;
    int t = threadIdx.x;  // 64 threads
    float invN = 1.0f / (float)N;
    float mu = stats[t] * invN;
    float var = stats[64 + t] * invN - mu * mu;
    float inv = rsqrtf(var + 1e-5f);
    float a = g3[t] * inv;
    float c = be3[t] - mu * a;
    float cn = cnt[gb];
    float p = (cn > 0.0f) ? (a * (pool[(size_t)gb * 64 + t] / cn) + c) : 0.0f;
    float o = 0.0f;
#pragma unroll
    for (int j = 0; j < 10; j++) {
        float part = p * Wf1[t * 10 + j];
#pragma unroll
        for (int off = 32; off > 0; off >>= 1) part += __shfl_down(part, off);
        float z = fmaxf(part + bf1[j], 0.0f);   // valid on lane 0 only
        o = fmaf(z, Wf2[j], o);
    }
    if (t == 0) out[gb] = o + bf2[0];
}

extern "C" void kernel_launch(void* const* d_in, const int* in_sizes, int n_in,
                              void* d_out, int out_size, void* d_ws, size_t ws_size,
                              hipStream_t stream) {
    const float* x      = (const float*)d_in[0];
    const int*   ei     = (const int*)d_in[1];
    const int*   batch  = (const int*)d_in[2];
    const float* W1a = (const float*)d_in[3];  const float* b1a = (const float*)d_in[4];
    const float* W1b = (const float*)d_in[5];  const float* b1b = (const float*)d_in[6];
    const float* e1  = (const float*)d_in[7];  const float* g1  = (const float*)d_in[8];
    const float* be1 = (const float*)d_in[9];
    const float* W2a = (const float*)d_in[10]; const float* b2a = (const float*)d_in[11];
    const float* W2b = (const float*)d_in[12]; const float* b2b = (const float*)d_in[13];
    const float* e2  = (const float*)d_in[14]; const float* g2  = (const float*)d_in[15];
    const float* be2 = (const float*)d_in[16];
    const float* W3a = (const float*)d_in[17]; const float* b3a = (const float*)d_in[18];
    const float* W3b = (const float*)d_in[19]; const float* b3b = (const float*)d_in[20];
    const float* e3  = (const float*)d_in[21]; const float* g3  = (const float*)d_in[22];
    const float* be3 = (const float*)d_in[23];
    const float* Wf1 = (const float*)d_in[24]; const float* bf1 = (const float*)d_in[25];
    const float* Wf2 = (const float*)d_in[26]; const float* bf2 = (const float*)d_in[27];

    const int N = in_sizes[2];
    const int E = in_sizes[1] / 2;
    const int G = out_size;

    // ---------- workspace layout ----------
    int* csr       = (int*)d_ws;               // E
    int* row_start = csr + E;                  // N+64
    int* cursor    = row_start + N + 64;       // N (init by scanwrite)
    int* bsum      = cursor + N;               // 256
    int* boff      = bsum + 256;               // 256
    // --- contiguous zero-init region ---
    int* deg       = boff + 256;               // N
    float* stats   = (float*)(deg + N);        // 3*128
    float* pool    = stats + 384;              // G*64
    float* cnt     = pool + (size_t)G * HD;    // G
    // --- end zero region ---
    float* aggr    = cnt + G;                  // N*64
    size_t NH = (size_t)N * HD;
    float* hA      = aggr + NH;                // N*64
    float* hB      = hA + NH;                  // N*64

    const int TB = 256;
    int nb = (N + 1023) / 1024;
    int fusedGrid = (N + 127) / 128;
    size_t zeroBytes = ((size_t)N + 384 + (size_t)G * HD + G) * sizeof(int);

    // ---------- CSR build (counting sort) ----------
    hipMemsetAsync(deg, 0, zeroBytes, stream);
    degree_kernel<<<(E + TB - 1) / TB, TB, 0, stream>>>(ei, deg, E);
    blocksum_kernel<<<nb, TB, 0, stream>>>(deg, bsum, N);
    scansums_kernel<<<1, 64, 0, stream>>>(bsum, boff, nb);
    scanwrite_kernel<<<nb, TB, 0, stream>>>(deg, boff, row_start, cursor, N);
    fill_kernel<<<(E + TB - 1) / TB, TB, 0, stream>>>(ei, cursor, csr, E);

    // ---------- layer 1: x(16) -> hA, stats1 ----------
    gather16_kernel<<<((N + 15) / 16 * 64 + TB - 1) / TB, TB, 0, stream>>>(x, row_start, csr, aggr, N);
    fused_mlp_kernel<16, false><<<fusedGrid, TB, 0, stream>>>(
        x, aggr, row_start, W1a, b1a, W1b, b1b, e1, nullptr, nullptr, nullptr, hA, stats, N);

    // ---------- layer 2: hA -> hB, BN1 folded ----------
    gather64_kernel<<<((N + 3) / 4 * 64 + TB - 1) / TB, TB, 0, stream>>>(hA, row_start, csr, aggr, N);
    fused_mlp_kernel<64, true><<<fusedGrid, TB, 0, stream>>>(
        hA, aggr, row_start, W2a, b2a, W2b, b2b, e2, stats, g1, be1, hB, stats + 128, N);

    // ---------- layer 3: hB -> hA, BN2 folded ----------
    gather64_kernel<<<((N + 3) / 4 * 64 + TB - 1) / TB, TB, 0, stream>>>(hB, row_start, csr, aggr, N);
    fused_mlp_kernel<64, true><<<fusedGrid, TB, 0, stream>>>(
        hB, aggr, row_start, W3a, b3a, W3b, b3b, e3, stats + 128, g2, be2, hA, stats + 256, N);

    // ---------- pool raw h3 (BN3 affine applied in readout) ----------
    int poolWaves = (N + 15) / 16;
    pool_seg_kernel<<<(poolWaves * 64 + TB - 1) / TB, TB, 0, stream>>>(hA, batch, pool, cnt, N);
    readout_kernel<<<G, 64, 0, stream>>>(pool, cnt, stats + 256, g3, be3,
                                         Wf1, bf1, Wf2, bf2, (float*)d_out, N);
}

// Round 8
// 447.581 us; speedup vs baseline: 2.2010x; 1.1929x over previous
//
#include <hip/hip_runtime.h>
#include <hip/hip_bf16.h>

// GIN net, round 8: CSR build rewritten as deterministic two-pass bucket sort
// (no global atomics, no sub-line scattered HBM writes). r6 lesson: contention
// per atomic ADDRESS is the cost driver (782 addrs = 284us). r7 lesson: 4B
// scattered stores amplify 16x across non-coherent XCD L2s (83MB for 4.8MB csr).
// This build: LDS histograms + per-(block,bucket) contiguous runs + within-L2
// bucket-local final scatter. Gathers/MLP/pool/readout unchanged from r7.

#define HD 64
#define NBLK 256     // edge-chunk blocks
#define BSH 9        // bucket = 512 nodes; requires N <= 131072 (src fits 17 bits)

// ---- K1: per-block LDS histogram over buckets ----
__global__ void hist_kernel(const int* __restrict__ ei, int* __restrict__ ghist, int E, int C) {
    __shared__ int lh[256];
    int b = blockIdx.x, tid = threadIdx.x;
    lh[tid] = 0;
    __syncthreads();
    int beg = b * C, end = min(beg + C, E);
    for (int i = beg + tid; i < end; i += 256) atomicAdd(&lh[ei[E + i] >> BSH], 1);
    __syncthreads();
    ghist[b * 256 + tid] = lh[tid];
}

// ---- K2: per-bucket exclusive scan over blocks (in place), totals out ----
__global__ void colscan_kernel(int* __restrict__ ghist, int* __restrict__ total) {
    __shared__ int s[256];
    int k = blockIdx.x, b = threadIdx.x;
    int v = ghist[b * 256 + k];
    s[b] = v;
    __syncthreads();
    for (int off = 1; off < 256; off <<= 1) {
        int u = (b >= off) ? s[b - off] : 0;
        __syncthreads();
        s[b] += u;
        __syncthreads();
    }
    ghist[b * 256 + k] = s[b] - v;     // exclusive prefix for (block b, bucket k)
    if (b == 255) total[k] = s[255];
}

// ---- K3: bucket base = exclusive scan of totals ----
__global__ void base_kernel(const int* __restrict__ total, int* __restrict__ bbase, int NBUCK) {
    __shared__ int s[256];
    int t = threadIdx.x;
    int v = (t < NBUCK) ? total[t] : 0;
    s[t] = v;
    __syncthreads();
    for (int off = 1; off < 256; off <<= 1) {
        int u = (t >= off) ? s[t - off] : 0;
        __syncthreads();
        s[t] += u;
        __syncthreads();
    }
    if (t == 0) bbase[0] = 0;
    bbase[t + 1] = s[t];
}

// ---- K4: scatter packed edges into bucket-grouped runs (LDS cursors only) ----
__global__ void scatter_kernel(const int* __restrict__ ei, const int* __restrict__ ghist,
                               const int* __restrict__ bbase, int* __restrict__ bpack,
                               int E, int C) {
    __shared__ int lcur[256];
    int b = blockIdx.x, tid = threadIdx.x;
    lcur[tid] = bbase[tid] + ghist[b * 256 + tid];
    __syncthreads();
    int beg = b * C, end = min(beg + C, E);
    for (int i = beg + tid; i < end; i += 256) {
        int src = ei[i], dst = ei[E + i];
        int pos = atomicAdd(&lcur[dst >> BSH], 1);
        bpack[pos] = src | ((dst & 511) << 17);
    }
}

// ---- K5: per-bucket CSR finalize (LDS hist512 + scan; bucket-local writes) ----
__global__ void csrbuild_kernel(const int* __restrict__ bpack, const int* __restrict__ bbase,
                                int* __restrict__ row_start, int* __restrict__ csr, int N) {
    __shared__ int h[512], s[512], lc[512];
    int k = blockIdx.x, tid = threadIdx.x;
    int beg = bbase[k], end = bbase[k + 1];
    h[tid] = 0; h[tid + 256] = 0;
    __syncthreads();
    for (int i = beg + tid; i < end; i += 256) atomicAdd(&h[(bpack[i] >> 17) & 511], 1);
    __syncthreads();
    s[tid] = h[tid]; s[tid + 256] = h[tid + 256];
    __syncthreads();
    for (int off = 1; off < 512; off <<= 1) {
        int v0 = (tid >= off) ? s[tid - off] : 0;
        int t1 = tid + 256;
        int v1 = (t1 >= off) ? s[t1 - off] : 0;
        __syncthreads();
        s[tid] += v0; s[t1] += v1;
        __syncthreads();
    }
    int e0 = s[tid] - h[tid], e1 = s[tid + 256] - h[tid + 256];
    lc[tid] = e0; lc[tid + 256] = e1;
    int n0 = (k << BSH) + tid, n1 = (k << BSH) + tid + 256;
    if (n0 < N) row_start[n0] = beg + e0;
    if (n1 < N) row_start[n1] = beg + e1;
    if (k == gridDim.x - 1 && tid == 0) row_start[N] = end;
    __syncthreads();
    for (int i = beg + tid; i < end; i += 256) {
        int v = bpack[i];
        int pos = beg + atomicAdd(&lc[(v >> 17) & 511], 1);
        csr[pos] = v & 0x1FFFF;
    }
}

// ======== gather: 16 lanes/node, float4/lane, 4-wide ILP unroll (r7) ========
__global__ void gather64_kernel(const float* __restrict__ x, const int* __restrict__ rs,
                                const int* __restrict__ csr, float* __restrict__ aggr, int N) {
    int lane = threadIdx.x & 63;
    int l4 = lane & 15;
    int wave = (blockIdx.x * blockDim.x + threadIdx.x) >> 6;
    int n = wave * 4 + (lane >> 4);
    if (n >= N) return;
    int beg = rs[n], end = rs[n + 1];
    const float* xb = x + (size_t)l4 * 4;
    float a0x = 0, a0y = 0, a0z = 0, a0w = 0;
    float a1x = 0, a1y = 0, a1z = 0, a1w = 0;
    float a2x = 0, a2y = 0, a2z = 0, a2w = 0;
    float a3x = 0, a3y = 0, a3z = 0, a3w = 0;
    for (int base = beg; base < end; base += 16) {
        int cnt = end - base; if (cnt > 16) cnt = 16;
        int e = (l4 < cnt) ? csr[base + l4] : 0;
        int j = 0;
        for (; j + 4 <= cnt; j += 4) {
            int s0 = __shfl(e, j + 0, 16);
            int s1 = __shfl(e, j + 1, 16);
            int s2 = __shfl(e, j + 2, 16);
            int s3 = __shfl(e, j + 3, 16);
            float4 v0 = *(const float4*)(xb + (size_t)s0 * 64);
            float4 v1 = *(const float4*)(xb + (size_t)s1 * 64);
            float4 v2 = *(const float4*)(xb + (size_t)s2 * 64);
            float4 v3 = *(const float4*)(xb + (size_t)s3 * 64);
            a0x += v0.x; a0y += v0.y; a0z += v0.z; a0w += v0.w;
            a1x += v1.x; a1y += v1.y; a1z += v1.z; a1w += v1.w;
            a2x += v2.x; a2y += v2.y; a2z += v2.z; a2w += v2.w;
            a3x += v3.x; a3y += v3.y; a3z += v3.z; a3w += v3.w;
        }
        for (; j < cnt; j++) {
            int s = __shfl(e, j, 16);
            float4 v = *(const float4*)(xb + (size_t)s * 64);
            a0x += v.x; a0y += v.y; a0z += v.z; a0w += v.w;
        }
    }
    float4 o;
    o.x = (a0x + a1x) + (a2x + a3x);
    o.y = (a0y + a1y) + (a2y + a3y);
    o.z = (a0z + a1z) + (a2z + a3z);
    o.w = (a0w + a1w) + (a2w + a3w);
    *reinterpret_cast<float4*>(aggr + (size_t)n * 64 + l4 * 4) = o;
}

__global__ void gather16_kernel(const float* __restrict__ x, const int* __restrict__ rs,
                                const int* __restrict__ csr, float* __restrict__ aggr, int N) {
    int lane = threadIdx.x & 63;
    int l4 = lane & 3;
    int wave = (blockIdx.x * blockDim.x + threadIdx.x) >> 6;
    int n = wave * 16 + (lane >> 2);
    if (n >= N) return;
    int beg = rs[n], end = rs[n + 1];
    const float* xb = x + (size_t)l4 * 4;
    float a0x = 0, a0y = 0, a0z = 0, a0w = 0;
    float a1x = 0, a1y = 0, a1z = 0, a1w = 0;
    float a2x = 0, a2y = 0, a2z = 0, a2w = 0;
    float a3x = 0, a3y = 0, a3z = 0, a3w = 0;
    for (int base = beg; base < end; base += 4) {
        int cnt = end - base; if (cnt > 4) cnt = 4;
        int e = (l4 < cnt) ? csr[base + l4] : 0;
        if (cnt == 4) {
            int s0 = __shfl(e, 0, 4);
            int s1 = __shfl(e, 1, 4);
            int s2 = __shfl(e, 2, 4);
            int s3 = __shfl(e, 3, 4);
            float4 v0 = *(const float4*)(xb + (size_t)s0 * 16);
            float4 v1 = *(const float4*)(xb + (size_t)s1 * 16);
            float4 v2 = *(const float4*)(xb + (size_t)s2 * 16);
            float4 v3 = *(const float4*)(xb + (size_t)s3 * 16);
            a0x += v0.x; a0y += v0.y; a0z += v0.z; a0w += v0.w;
            a1x += v1.x; a1y += v1.y; a1z += v1.z; a1w += v1.w;
            a2x += v2.x; a2y += v2.y; a2z += v2.z; a2w += v2.w;
            a3x += v3.x; a3y += v3.y; a3z += v3.z; a3w += v3.w;
        } else {
            for (int j = 0; j < cnt; j++) {
                int s = __shfl(e, j, 4);
                float4 v = *(const float4*)(xb + (size_t)s * 16);
                a0x += v.x; a0y += v.y; a0z += v.z; a0w += v.w;
            }
        }
    }
    float4 o;
    o.x = (a0x + a1x) + (a2x + a3x);
    o.y = (a0y + a1y) + (a2y + a3y);
    o.z = (a0z + a1z) + (a2z + a3z);
    o.w = (a0w + a1w) + (a2w + a3w);
    *reinterpret_cast<float4*>(aggr + (size_t)n * 16 + l4 * 4) = o;
}

// ======== fused MLP: 4x4 register tile, k-major LDS, prep (BN fold) inlined ========
template <int DIN, bool AFF>
__launch_bounds__(256)
__global__ void fused_mlp_kernel(const float* __restrict__ xin, const float* __restrict__ aggr,
                                 const int* __restrict__ rs,
                                 const float* __restrict__ Wa, const float* __restrict__ ba,
                                 const float* __restrict__ Wb, const float* __restrict__ bb,
                                 const float* __restrict__ epsp,
                                 const float* __restrict__ statsPrev,
                                 const float* __restrict__ gPrev, const float* __restrict__ bePrev,
                                 float* __restrict__ hout, float* __restrict__ stats, int N) {
    __shared__ float Wa_s[DIN * 64];
    __shared__ float Wb_s[64 * 64];
    __shared__ float zts[64 * 68];
    __shared__ float statS[128];
    __shared__ float degS[64];
    __shared__ float aS[64], cS[64], uS[64];

    const int tid = threadIdx.x;
    const int tc = tid & 15;
    const int tn = tid >> 4;

    if (AFF) {
        if (tid < 64) {
            float invN = 1.0f / (float)N;
            float mu = statsPrev[tid] * invN;
            float var = statsPrev[64 + tid] * invN - mu * mu;
            float inv = rsqrtf(var + 1e-5f);
            float a = gPrev[tid] * inv;
            aS[tid] = a;
            cS[tid] = bePrev[tid] - mu * a;
        }
        __syncthreads();
        for (int i = tid; i < DIN * 64; i += 256) Wa_s[i] = aS[i >> 6] * Wa[i];
        if (tid < 64) {
            float s = 0.0f;
            for (int k = 0; k < 64; k++) s = fmaf(cS[k], Wa[k * 64 + tid], s);
            uS[tid] = s;
        }
    } else {
        for (int i = tid; i < DIN * 64; i += 256) Wa_s[i] = Wa[i];
    }
    for (int i = tid; i < 64 * 64; i += 256) Wb_s[i] = Wb[i];
    if (tid < 128) statS[tid] = 0.0f;
    const float e1 = 1.0f + epsp[0];
    __syncthreads();

    float4 t4;
    t4 = *(const float4*)&ba[tc * 4];
    const float bav[4] = {t4.x, t4.y, t4.z, t4.w};
    t4 = *(const float4*)&bb[tc * 4];
    const float bbv[4] = {t4.x, t4.y, t4.z, t4.w};
    float uv[4] = {0, 0, 0, 0};
    if (AFF) { uv[0] = uS[tc * 4]; uv[1] = uS[tc * 4 + 1]; uv[2] = uS[tc * 4 + 2]; uv[3] = uS[tc * 4 + 3]; }

    float sv[4] = {0, 0, 0, 0}, qv[4] = {0, 0, 0, 0};

    const int ITER = 2;
    int blockBase = blockIdx.x * (64 * ITER);
    for (int it = 0; it < ITER; ++it) {
        int gbase = blockBase + it * 64;
        float zr[4][4];
        if (DIN == 64) {
#pragma unroll
            for (int i = 0; i < 4; ++i) {
                int node = gbase + tn * 4 + i;
                float4 xv = {0, 0, 0, 0}, av = {0, 0, 0, 0};
                if (node < N) {
                    xv = *(const float4*)&xin[(size_t)node * 64 + tc * 4];
                    av = *(const float4*)&aggr[(size_t)node * 64 + tc * 4];
                }
                zr[i][0] = fmaf(e1, xv.x, av.x);
                zr[i][1] = fmaf(e1, xv.y, av.y);
                zr[i][2] = fmaf(e1, xv.z, av.z);
                zr[i][3] = fmaf(e1, xv.w, av.w);
            }
        } else {
            int node = gbase + tn * 4 + (tc >> 2);
            float4 xv = {0, 0, 0, 0}, av = {0, 0, 0, 0};
            if (node < N) {
                xv = *(const float4*)&xin[(size_t)node * 16 + (tc & 3) * 4];
                av = *(const float4*)&aggr[(size_t)node * 16 + (tc & 3) * 4];
            }
            zr[0][0] = fmaf(e1, xv.x, av.x);
            zr[0][1] = fmaf(e1, xv.y, av.y);
            zr[0][2] = fmaf(e1, xv.z, av.z);
            zr[0][3] = fmaf(e1, xv.w, av.w);
        }
        float dg[4];
        if (AFF && tid < 64) {
            int node = gbase + tid;
            degS[tid] = (node < N) ? (float)(rs[node + 1] - rs[node]) : 0.0f;
        }
        __syncthreads();                       // bar0
        if (DIN == 64) {
#pragma unroll
            for (int j = 0; j < 4; ++j) {
                float4 w = {zr[0][j], zr[1][j], zr[2][j], zr[3][j]};
                *(float4*)&zts[(tc * 4 + j) * 68 + tn * 4] = w;
            }
        } else {
#pragma unroll
            for (int j = 0; j < 4; ++j)
                zts[((tc & 3) * 4 + j) * 68 + tn * 4 + (tc >> 2)] = zr[0][j];
        }
        __syncthreads();                       // bar1
        if (AFF) {
#pragma unroll
            for (int i = 0; i < 4; ++i) dg[i] = e1 + degS[tn * 4 + i];
        }
        float ac[4][4];
#pragma unroll
        for (int i = 0; i < 4; ++i)
#pragma unroll
            for (int j = 0; j < 4; ++j)
                ac[i][j] = AFF ? fmaf(dg[i], uv[j], bav[j]) : bav[j];
#pragma unroll 8
        for (int k = 0; k < DIN; ++k) {
            float4 zv = *(const float4*)&zts[k * 68 + tn * 4];
            float4 wv = *(const float4*)&Wa_s[k * 64 + tc * 4];
            const float zf[4] = {zv.x, zv.y, zv.z, zv.w};
            const float wf[4] = {wv.x, wv.y, wv.z, wv.w};
#pragma unroll
            for (int i = 0; i < 4; ++i)
#pragma unroll
                for (int j = 0; j < 4; ++j)
                    ac[i][j] = fmaf(zf[i], wf[j], ac[i][j]);
        }
#pragma unroll
        for (int i = 0; i < 4; ++i)
#pragma unroll
            for (int j = 0; j < 4; ++j)
                ac[i][j] = fmaxf(ac[i][j], 0.0f);
        __syncthreads();                       // bar2
#pragma unroll
        for (int j = 0; j < 4; ++j) {
            float4 w = {ac[0][j], ac[1][j], ac[2][j], ac[3][j]};
            *(float4*)&zts[(tc * 4 + j) * 68 + tn * 4] = w;
        }
        __syncthreads();                       // bar3
        float hc[4][4];
#pragma unroll
        for (int i = 0; i < 4; ++i)
#pragma unroll
            for (int j = 0; j < 4; ++j)
                hc[i][j] = bbv[j];
#pragma unroll 8
        for (int k = 0; k < 64; ++k) {
            float4 tv = *(const float4*)&zts[k * 68 + tn * 4];
            float4 wv = *(const float4*)&Wb_s[k * 64 + tc * 4];
            const float tf[4] = {tv.x, tv.y, tv.z, tv.w};
            const float wf[4] = {wv.x, wv.y, wv.z, wv.w};
#pragma unroll
            for (int i = 0; i < 4; ++i)
#pragma unroll
                for (int j = 0; j < 4; ++j)
                    hc[i][j] = fmaf(tf[i], wf[j], hc[i][j]);
        }
#pragma unroll
        for (int i = 0; i < 4; ++i) {
            int node = gbase + tn * 4 + i;
            if (node < N) {
                float4 o;
                o.x = fmaxf(hc[i][0], 0.0f); o.y = fmaxf(hc[i][1], 0.0f);
                o.z = fmaxf(hc[i][2], 0.0f); o.w = fmaxf(hc[i][3], 0.0f);
                *(float4*)&hout[(size_t)node * 64 + tc * 4] = o;
                sv[0] += o.x; sv[1] += o.y; sv[2] += o.z; sv[3] += o.w;
                qv[0] += o.x * o.x; qv[1] += o.y * o.y; qv[2] += o.z * o.z; qv[3] += o.w * o.w;
            }
        }
    }
#pragma unroll
    for (int off = 16; off < 64; off <<= 1) {
#pragma unroll
        for (int j = 0; j < 4; ++j) {
            sv[j] += __shfl_xor(sv[j], off);
            qv[j] += __shfl_xor(qv[j], off);
        }
    }
    if ((tid & 63) < 16) {
#pragma unroll
        for (int j = 0; j < 4; ++j) {
            atomicAdd(&statS[tc * 4 + j], sv[j]);
            atomicAdd(&statS[64 + tc * 4 + j], qv[j]);
        }
    }
    __syncthreads();
    if (tid < 128) unsafeAtomicAdd(&stats[tid], statS[tid]);
}

// ================= segmented pool (batch sorted) =================
__global__ void pool_seg_kernel(const float* __restrict__ h, const int* __restrict__ batch,
                                float* __restrict__ pool, float* __restrict__ cnt, int N) {
    int lane = threadIdx.x & 63;
    int wave = (blockIdx.x * blockDim.x + threadIdx.x) >> 6;
    int base = wave * 16;
    if (base >= N) return;
    int end = base + 16; if (end > N) end = N;
    int cur = batch[base];
    float acc = 0.0f;
    int run = 0;
    for (int n = base; n < end; n++) {
        int gid = batch[n];
        if (gid != cur) {
            unsafeAtomicAdd(&pool[(size_t)cur * 64 + lane], acc);
            if (lane == 0) unsafeAtomicAdd(&cnt[cur], (float)run);
            acc = 0.0f; run = 0; cur = gid;
        }
        acc += h[(size_t)n * 64 + lane];
        run++;
    }
    unsafeAtomicAdd(&pool[(size_t)cur * 64 + lane], acc);
    if (lane == 0) unsafeAtomicAdd(&cnt[cur], (float)run);
}

// ================= readout (applies BN3 affine to pooled mean) =================
__global__ void readout_kernel(const float* __restrict__ pool, const float* __restrict__ cnt,
                               const float* __restrict__ stats, const float* __restrict__ g3,
                               const float* __restrict__ be3,
                               const float* __restrict__ Wf1, const float* __restrict__ bf1,
                               const float* __restrict__ Wf2, const float* __restrict__ bf2,
                               float* __restrict__ out, int N) {
    int gb = blockIdx.x;
    int t = threadIdx.x;  // 64 threads
    float invN = 1.0f / (float)N;
    float mu = stats[t] * invN;
    float var = stats[64 + t] * invN - mu * mu;
    float inv = rsqrtf(var + 1e-5f);
    float a = g3[t] * inv;
    float c = be3[t] - mu * a;
    float cn = cnt[gb];
    float p = (cn > 0.0f) ? (a * (pool[(size_t)gb * 64 + t] / cn) + c) : 0.0f;
    float o = 0.0f;
#pragma unroll
    for (int j = 0; j < 10; j++) {
        float part = p * Wf1[t * 10 + j];
#pragma unroll
        for (int off = 32; off > 0; off >>= 1) part += __shfl_down(part, off);
        float z = fmaxf(part + bf1[j], 0.0f);   // valid on lane 0 only
        o = fmaf(z, Wf2[j], o);
    }
    if (t == 0) out[gb] = o + bf2[0];
}

extern "C" void kernel_launch(void* const* d_in, const int* in_sizes, int n_in,
                              void* d_out, int out_size, void* d_ws, size_t ws_size,
                              hipStream_t stream) {
    const float* x      = (const float*)d_in[0];
    const int*   ei     = (const int*)d_in[1];
    const int*   batch  = (const int*)d_in[2];
    const float* W1a = (const float*)d_in[3];  const float* b1a = (const float*)d_in[4];
    const float* W1b = (const float*)d_in[5];  const float* b1b = (const float*)d_in[6];
    const float* e1  = (const float*)d_in[7];  const float* g1  = (const float*)d_in[8];
    const float* be1 = (const float*)d_in[9];
    const float* W2a = (const float*)d_in[10]; const float* b2a = (const float*)d_in[11];
    const float* W2b = (const float*)d_in[12]; const float* b2b = (const float*)d_in[13];
    const float* e2  = (const float*)d_in[14]; const float* g2  = (const float*)d_in[15];
    const float* be2 = (const float*)d_in[16];
    const float* W3a = (const float*)d_in[17]; const float* b3a = (const float*)d_in[18];
    const float* W3b = (const float*)d_in[19]; const float* b3b = (const float*)d_in[20];
    const float* e3  = (const float*)d_in[21]; const float* g3  = (const float*)d_in[22];
    const float* be3 = (const float*)d_in[23];
    const float* Wf1 = (const float*)d_in[24]; const float* bf1 = (const float*)d_in[25];
    const float* Wf2 = (const float*)d_in[26]; const float* bf2 = (const float*)d_in[27];

    const int N = in_sizes[2];
    const int E = in_sizes[1] / 2;
    const int G = out_size;
    const int NBUCK = (N + 511) >> BSH;        // 196 for N=100000 (<=256)
    const int C = (E + NBLK - 1) / NBLK;       // edges per chunk block

    // ---------- workspace layout ----------
    int* csr       = (int*)d_ws;               // E
    int* row_start = csr + E;                  // N+64
    int* bpack     = row_start + N + 64;       // E
    int* ghist     = bpack + E;                // NBLK*256
    int* total     = ghist + NBLK * 256;       // 256
    int* bbase     = total + 256;              // 272 (need NBUCK+1, K3 writes 257)
    // --- contiguous zero-init region ---
    float* stats   = (float*)(bbase + 272);    // 3*128
    float* pool    = stats + 384;              // G*64
    float* cnt     = pool + (size_t)G * HD;    // G
    // --- end zero region ---
    float* aggr    = cnt + G;                  // N*64
    size_t NH = (size_t)N * HD;
    float* hA      = aggr + NH;                // N*64
    float* hB      = hA + NH;                  // N*64

    const int TB = 256;
    int fusedGrid = (N + 127) / 128;
    size_t zeroBytes = (size_t)(384 + (size_t)G * HD + G) * sizeof(float);

    // ---------- CSR build (deterministic two-pass bucket sort) ----------
    hipMemsetAsync(stats, 0, zeroBytes, stream);
    hist_kernel<<<NBLK, 256, 0, stream>>>(ei, ghist, E, C);
    colscan_kernel<<<NBUCK, 256, 0, stream>>>(ghist, total);
    base_kernel<<<1, 256, 0, stream>>>(total, bbase, NBUCK);
    scatter_kernel<<<NBLK, 256, 0, stream>>>(ei, ghist, bbase, bpack, E, C);
    csrbuild_kernel<<<NBUCK, 256, 0, stream>>>(bpack, bbase, row_start, csr, N);

    // ---------- layer 1: x(16) -> hA, stats1 ----------
    gather16_kernel<<<((N + 15) / 16 * 64 + TB - 1) / TB, TB, 0, stream>>>(x, row_start, csr, aggr, N);
    fused_mlp_kernel<16, false><<<fusedGrid, TB, 0, stream>>>(
        x, aggr, row_start, W1a, b1a, W1b, b1b, e1, nullptr, nullptr, nullptr, hA, stats, N);

    // ---------- layer 2: hA -> hB, BN1 folded ----------
    gather64_kernel<<<((N + 3) / 4 * 64 + TB - 1) / TB, TB, 0, stream>>>(hA, row_start, csr, aggr, N);
    fused_mlp_kernel<64, true><<<fusedGrid, TB, 0, stream>>>(
        hA, aggr, row_start, W2a, b2a, W2b, b2b, e2, stats, g1, be1, hB, stats + 128, N);

    // ---------- layer 3: hB -> hA, BN2 folded ----------
    gather64_kernel<<<((N + 3) / 4 * 64 + TB - 1) / TB, TB, 0, stream>>>(hB, row_start, csr, aggr, N);
    fused_mlp_kernel<64, true><<<fusedGrid, TB, 0, stream>>>(
        hB, aggr, row_start, W3a, b3a, W3b, b3b, e3, stats + 128, g2, be2, hA, stats + 256, N);

    // ---------- pool raw h3 (BN3 affine applied in readout) ----------
    int poolWaves = (N + 15) / 16;
    pool_seg_kernel<<<(poolWaves * 64 + TB - 1) / TB, TB, 0, stream>>>(hA, batch, pool, cnt, N);
    readout_kernel<<<G, 64, 0, stream>>>(pool, cnt, stats + 256, g3, be3,
                                         Wf1, bf1, Wf2, bf2, (float*)d_out, N);
}

// Round 9
// 406.608 us; speedup vs baseline: 2.4228x; 1.1008x over previous
//
#include <hip/hip_runtime.h>
#include <hip/hip_bf16.h>

// GIN net, round 9: bf16 intermediate node features (h1,h2,h3). The gather is
// memory-traffic bound (r8: 192MB fetch/dispatch, 45% HBM peak) and each edge
// must fetch its src row -> halve the row (256B f32 -> 128B bf16). All
// accumulation stays f32 (aggr buffer, MLP registers, stats, pool); only the
// stored features are bf16. Error budget: ~0.06% rel per layer << 4e-3 thresh.
// CSR build (deterministic bucket sort), MLP structure, pool, readout as r8.

#define HD 64
#define NBLK 256     // edge-chunk blocks
#define BSH 9        // bucket = 512 nodes; requires N <= 131072 (src fits 17 bits)

typedef unsigned short u16;

__device__ __forceinline__ float bf2f(u16 u) {
    return __uint_as_float(((unsigned int)u) << 16);
}
__device__ __forceinline__ u16 f2bf(float f) {       // round-to-nearest-even
    unsigned int u = __float_as_uint(f);
    unsigned int r = 0x7FFFu + ((u >> 16) & 1u);
    return (u16)((u + r) >> 16);
}

// ================= CSR build: deterministic two-pass bucket sort (r8) ============
__global__ void hist_kernel(const int* __restrict__ ei, int* __restrict__ ghist, int E, int C) {
    __shared__ int lh[256];
    int b = blockIdx.x, tid = threadIdx.x;
    lh[tid] = 0;
    __syncthreads();
    int beg = b * C, end = min(beg + C, E);
    for (int i = beg + tid; i < end; i += 256) atomicAdd(&lh[ei[E + i] >> BSH], 1);
    __syncthreads();
    ghist[b * 256 + tid] = lh[tid];
}

__global__ void colscan_kernel(int* __restrict__ ghist, int* __restrict__ total) {
    __shared__ int s[256];
    int k = blockIdx.x, b = threadIdx.x;
    int v = ghist[b * 256 + k];
    s[b] = v;
    __syncthreads();
    for (int off = 1; off < 256; off <<= 1) {
        int u = (b >= off) ? s[b - off] : 0;
        __syncthreads();
        s[b] += u;
        __syncthreads();
    }
    ghist[b * 256 + k] = s[b] - v;
    if (b == 255) total[k] = s[255];
}

__global__ void base_kernel(const int* __restrict__ total, int* __restrict__ bbase, int NBUCK) {
    __shared__ int s[256];
    int t = threadIdx.x;
    int v = (t < NBUCK) ? total[t] : 0;
    s[t] = v;
    __syncthreads();
    for (int off = 1; off < 256; off <<= 1) {
        int u = (t >= off) ? s[t - off] : 0;
        __syncthreads();
        s[t] += u;
        __syncthreads();
    }
    if (t == 0) bbase[0] = 0;
    bbase[t + 1] = s[t];
}

__global__ void scatter_kernel(const int* __restrict__ ei, const int* __restrict__ ghist,
                               const int* __restrict__ bbase, int* __restrict__ bpack,
                               int E, int C) {
    __shared__ int lcur[256];
    int b = blockIdx.x, tid = threadIdx.x;
    lcur[tid] = bbase[tid] + ghist[b * 256 + tid];
    __syncthreads();
    int beg = b * C, end = min(beg + C, E);
    for (int i = beg + tid; i < end; i += 256) {
        int src = ei[i], dst = ei[E + i];
        int pos = atomicAdd(&lcur[dst >> BSH], 1);
        bpack[pos] = src | ((dst & 511) << 17);
    }
}

__global__ void csrbuild_kernel(const int* __restrict__ bpack, const int* __restrict__ bbase,
                                int* __restrict__ row_start, int* __restrict__ csr, int N) {
    __shared__ int h[512], s[512], lc[512];
    int k = blockIdx.x, tid = threadIdx.x;
    int beg = bbase[k], end = bbase[k + 1];
    h[tid] = 0; h[tid + 256] = 0;
    __syncthreads();
    for (int i = beg + tid; i < end; i += 256) atomicAdd(&h[(bpack[i] >> 17) & 511], 1);
    __syncthreads();
    s[tid] = h[tid]; s[tid + 256] = h[tid + 256];
    __syncthreads();
    for (int off = 1; off < 512; off <<= 1) {
        int v0 = (tid >= off) ? s[tid - off] : 0;
        int t1 = tid + 256;
        int v1 = (t1 >= off) ? s[t1 - off] : 0;
        __syncthreads();
        s[tid] += v0; s[t1] += v1;
        __syncthreads();
    }
    int e0 = s[tid] - h[tid], e1 = s[tid + 256] - h[tid + 256];
    lc[tid] = e0; lc[tid + 256] = e1;
    int n0 = (k << BSH) + tid, n1 = (k << BSH) + tid + 256;
    if (n0 < N) row_start[n0] = beg + e0;
    if (n1 < N) row_start[n1] = beg + e1;
    if (k == gridDim.x - 1 && tid == 0) row_start[N] = end;
    __syncthreads();
    for (int i = beg + tid; i < end; i += 256) {
        int v = bpack[i];
        int pos = beg + atomicAdd(&lc[(v >> 17) & 511], 1);
        csr[pos] = v & 0x1FFFF;
    }
}

// ======== gather64: bf16 rows, 16 lanes/node, ushort4/lane, 4-wide ILP ========
__global__ void gather64_kernel(const u16* __restrict__ x, const int* __restrict__ rs,
                                const int* __restrict__ csr, float* __restrict__ aggr, int N) {
    int lane = threadIdx.x & 63;
    int l4 = lane & 15;
    int wave = (blockIdx.x * blockDim.x + threadIdx.x) >> 6;
    int n = wave * 4 + (lane >> 4);
    if (n >= N) return;
    int beg = rs[n], end = rs[n + 1];
    const u16* xb = x + (size_t)l4 * 4;
    float a0x = 0, a0y = 0, a0z = 0, a0w = 0;
    float a1x = 0, a1y = 0, a1z = 0, a1w = 0;
    float a2x = 0, a2y = 0, a2z = 0, a2w = 0;
    float a3x = 0, a3y = 0, a3z = 0, a3w = 0;
    for (int base = beg; base < end; base += 16) {
        int cnt = end - base; if (cnt > 16) cnt = 16;
        int e = (l4 < cnt) ? csr[base + l4] : 0;
        int j = 0;
        for (; j + 4 <= cnt; j += 4) {
            int s0 = __shfl(e, j + 0, 16);
            int s1 = __shfl(e, j + 1, 16);
            int s2 = __shfl(e, j + 2, 16);
            int s3 = __shfl(e, j + 3, 16);
            ushort4 u0 = *(const ushort4*)(xb + (size_t)s0 * 64);
            ushort4 u1 = *(const ushort4*)(xb + (size_t)s1 * 64);
            ushort4 u2 = *(const ushort4*)(xb + (size_t)s2 * 64);
            ushort4 u3 = *(const ushort4*)(xb + (size_t)s3 * 64);
            a0x += bf2f(u0.x); a0y += bf2f(u0.y); a0z += bf2f(u0.z); a0w += bf2f(u0.w);
            a1x += bf2f(u1.x); a1y += bf2f(u1.y); a1z += bf2f(u1.z); a1w += bf2f(u1.w);
            a2x += bf2f(u2.x); a2y += bf2f(u2.y); a2z += bf2f(u2.z); a2w += bf2f(u2.w);
            a3x += bf2f(u3.x); a3y += bf2f(u3.y); a3z += bf2f(u3.z); a3w += bf2f(u3.w);
        }
        for (; j < cnt; j++) {
            int s = __shfl(e, j, 16);
            ushort4 u = *(const ushort4*)(xb + (size_t)s * 64);
            a0x += bf2f(u.x); a0y += bf2f(u.y); a0z += bf2f(u.z); a0w += bf2f(u.w);
        }
    }
    float4 o;
    o.x = (a0x + a1x) + (a2x + a3x);
    o.y = (a0y + a1y) + (a2y + a3y);
    o.z = (a0z + a1z) + (a2z + a3z);
    o.w = (a0w + a1w) + (a2w + a3w);
    *reinterpret_cast<float4*>(aggr + (size_t)n * 64 + l4 * 4) = o;
}

// gather16: layer-1 input x is f32 (harness-provided), unchanged from r8
__global__ void gather16_kernel(const float* __restrict__ x, const int* __restrict__ rs,
                                const int* __restrict__ csr, float* __restrict__ aggr, int N) {
    int lane = threadIdx.x & 63;
    int l4 = lane & 3;
    int wave = (blockIdx.x * blockDim.x + threadIdx.x) >> 6;
    int n = wave * 16 + (lane >> 2);
    if (n >= N) return;
    int beg = rs[n], end = rs[n + 1];
    const float* xb = x + (size_t)l4 * 4;
    float a0x = 0, a0y = 0, a0z = 0, a0w = 0;
    float a1x = 0, a1y = 0, a1z = 0, a1w = 0;
    float a2x = 0, a2y = 0, a2z = 0, a2w = 0;
    float a3x = 0, a3y = 0, a3z = 0, a3w = 0;
    for (int base = beg; base < end; base += 4) {
        int cnt = end - base; if (cnt > 4) cnt = 4;
        int e = (l4 < cnt) ? csr[base + l4] : 0;
        if (cnt == 4) {
            int s0 = __shfl(e, 0, 4);
            int s1 = __shfl(e, 1, 4);
            int s2 = __shfl(e, 2, 4);
            int s3 = __shfl(e, 3, 4);
            float4 v0 = *(const float4*)(xb + (size_t)s0 * 16);
            float4 v1 = *(const float4*)(xb + (size_t)s1 * 16);
            float4 v2 = *(const float4*)(xb + (size_t)s2 * 16);
            float4 v3 = *(const float4*)(xb + (size_t)s3 * 16);
            a0x += v0.x; a0y += v0.y; a0z += v0.z; a0w += v0.w;
            a1x += v1.x; a1y += v1.y; a1z += v1.z; a1w += v1.w;
            a2x += v2.x; a2y += v2.y; a2z += v2.z; a2w += v2.w;
            a3x += v3.x; a3y += v3.y; a3z += v3.z; a3w += v3.w;
        } else {
            for (int j = 0; j < cnt; j++) {
                int s = __shfl(e, j, 4);
                float4 v = *(const float4*)(xb + (size_t)s * 16);
                a0x += v.x; a0y += v.y; a0z += v.z; a0w += v.w;
            }
        }
    }
    float4 o;
    o.x = (a0x + a1x) + (a2x + a3x);
    o.y = (a0y + a1y) + (a2y + a3y);
    o.z = (a0z + a1z) + (a2z + a3z);
    o.w = (a0w + a1w) + (a2w + a3w);
    *reinterpret_cast<float4*>(aggr + (size_t)n * 16 + l4 * 4) = o;
}

// ======== fused MLP (r8 structure): bf16 xin for DIN=64, bf16 hout ========
// xin_: DIN==16 -> const float* (x), DIN==64 -> const u16* (bf16 h)
template <int DIN, bool AFF>
__launch_bounds__(256)
__global__ void fused_mlp_kernel(const void* __restrict__ xin_, const float* __restrict__ aggr,
                                 const int* __restrict__ rs,
                                 const float* __restrict__ Wa, const float* __restrict__ ba,
                                 const float* __restrict__ Wb, const float* __restrict__ bb,
                                 const float* __restrict__ epsp,
                                 const float* __restrict__ statsPrev,
                                 const float* __restrict__ gPrev, const float* __restrict__ bePrev,
                                 u16* __restrict__ hout, float* __restrict__ stats, int N) {
    __shared__ float Wa_s[DIN * 64];
    __shared__ float Wb_s[64 * 64];
    __shared__ float zts[64 * 68];
    __shared__ float statS[128];
    __shared__ float degS[64];
    __shared__ float aS[64], cS[64], uS[64];

    const int tid = threadIdx.x;
    const int tc = tid & 15;
    const int tn = tid >> 4;
    const float* xinF = (const float*)xin_;
    const u16*   xinB = (const u16*)xin_;

    if (AFF) {
        if (tid < 64) {
            float invN = 1.0f / (float)N;
            float mu = statsPrev[tid] * invN;
            float var = statsPrev[64 + tid] * invN - mu * mu;
            float inv = rsqrtf(var + 1e-5f);
            float a = gPrev[tid] * inv;
            aS[tid] = a;
            cS[tid] = bePrev[tid] - mu * a;
        }
        __syncthreads();
        for (int i = tid; i < DIN * 64; i += 256) Wa_s[i] = aS[i >> 6] * Wa[i];
        if (tid < 64) {
            float s = 0.0f;
            for (int k = 0; k < 64; k++) s = fmaf(cS[k], Wa[k * 64 + tid], s);
            uS[tid] = s;
        }
    } else {
        for (int i = tid; i < DIN * 64; i += 256) Wa_s[i] = Wa[i];
    }
    for (int i = tid; i < 64 * 64; i += 256) Wb_s[i] = Wb[i];
    if (tid < 128) statS[tid] = 0.0f;
    const float e1 = 1.0f + epsp[0];
    __syncthreads();

    float4 t4;
    t4 = *(const float4*)&ba[tc * 4];
    const float bav[4] = {t4.x, t4.y, t4.z, t4.w};
    t4 = *(const float4*)&bb[tc * 4];
    const float bbv[4] = {t4.x, t4.y, t4.z, t4.w};
    float uv[4] = {0, 0, 0, 0};
    if (AFF) { uv[0] = uS[tc * 4]; uv[1] = uS[tc * 4 + 1]; uv[2] = uS[tc * 4 + 2]; uv[3] = uS[tc * 4 + 3]; }

    float sv[4] = {0, 0, 0, 0}, qv[4] = {0, 0, 0, 0};

    const int ITER = 2;
    int blockBase = blockIdx.x * (64 * ITER);
    for (int it = 0; it < ITER; ++it) {
        int gbase = blockBase + it * 64;
        float zr[4][4];
        if (DIN == 64) {
#pragma unroll
            for (int i = 0; i < 4; ++i) {
                int node = gbase + tn * 4 + i;
                float4 av = {0, 0, 0, 0};
                float xf[4] = {0, 0, 0, 0};
                if (node < N) {
                    ushort4 xu = *(const ushort4*)&xinB[(size_t)node * 64 + tc * 4];
                    xf[0] = bf2f(xu.x); xf[1] = bf2f(xu.y); xf[2] = bf2f(xu.z); xf[3] = bf2f(xu.w);
                    av = *(const float4*)&aggr[(size_t)node * 64 + tc * 4];
                }
                zr[i][0] = fmaf(e1, xf[0], av.x);
                zr[i][1] = fmaf(e1, xf[1], av.y);
                zr[i][2] = fmaf(e1, xf[2], av.z);
                zr[i][3] = fmaf(e1, xf[3], av.w);
            }
        } else {
            int node = gbase + tn * 4 + (tc >> 2);
            float4 xv = {0, 0, 0, 0}, av = {0, 0, 0, 0};
            if (node < N) {
                xv = *(const float4*)&xinF[(size_t)node * 16 + (tc & 3) * 4];
                av = *(const float4*)&aggr[(size_t)node * 16 + (tc & 3) * 4];
            }
            zr[0][0] = fmaf(e1, xv.x, av.x);
            zr[0][1] = fmaf(e1, xv.y, av.y);
            zr[0][2] = fmaf(e1, xv.z, av.z);
            zr[0][3] = fmaf(e1, xv.w, av.w);
        }
        float dg[4];
        if (AFF && tid < 64) {
            int node = gbase + tid;
            degS[tid] = (node < N) ? (float)(rs[node + 1] - rs[node]) : 0.0f;
        }
        __syncthreads();                       // bar0
        if (DIN == 64) {
#pragma unroll
            for (int j = 0; j < 4; ++j) {
                float4 w = {zr[0][j], zr[1][j], zr[2][j], zr[3][j]};
                *(float4*)&zts[(tc * 4 + j) * 68 + tn * 4] = w;
            }
        } else {
#pragma unroll
            for (int j = 0; j < 4; ++j)
                zts[((tc & 3) * 4 + j) * 68 + tn * 4 + (tc >> 2)] = zr[0][j];
        }
        __syncthreads();                       // bar1
        if (AFF) {
#pragma unroll
            for (int i = 0; i < 4; ++i) dg[i] = e1 + degS[tn * 4 + i];
        }
        float ac[4][4];
#pragma unroll
        for (int i = 0; i < 4; ++i)
#pragma unroll
            for (int j = 0; j < 4; ++j)
                ac[i][j] = AFF ? fmaf(dg[i], uv[j], bav[j]) : bav[j];
#pragma unroll 8
        for (int k = 0; k < DIN; ++k) {
            float4 zv = *(const float4*)&zts[k * 68 + tn * 4];
            float4 wv = *(const float4*)&Wa_s[k * 64 + tc * 4];
            const float zf[4] = {zv.x, zv.y, zv.z, zv.w};
            const float wf[4] = {wv.x, wv.y, wv.z, wv.w};
#pragma unroll
            for (int i = 0; i < 4; ++i)
#pragma unroll
                for (int j = 0; j < 4; ++j)
                    ac[i][j] = fmaf(zf[i], wf[j], ac[i][j]);
        }
#pragma unroll
        for (int i = 0; i < 4; ++i)
#pragma unroll
            for (int j = 0; j < 4; ++j)
                ac[i][j] = fmaxf(ac[i][j], 0.0f);
        __syncthreads();                       // bar2
#pragma unroll
        for (int j = 0; j < 4; ++j) {
            float4 w = {ac[0][j], ac[1][j], ac[2][j], ac[3][j]};
            *(float4*)&zts[(tc * 4 + j) * 68 + tn * 4] = w;
        }
        __syncthreads();                       // bar3
        float hc[4][4];
#pragma unroll
        for (int i = 0; i < 4; ++i)
#pragma unroll
            for (int j = 0; j < 4; ++j)
                hc[i][j] = bbv[j];
#pragma unroll 8
        for (int k = 0; k < 64; ++k) {
            float4 tv = *(const float4*)&zts[k * 68 + tn * 4];
            float4 wv = *(const float4*)&Wb_s[k * 64 + tc * 4];
            const float tf[4] = {tv.x, tv.y, tv.z, tv.w};
            const float wf[4] = {wv.x, wv.y, wv.z, wv.w};
#pragma unroll
            for (int i = 0; i < 4; ++i)
#pragma unroll
                for (int j = 0; j < 4; ++j)
                    hc[i][j] = fmaf(tf[i], wf[j], hc[i][j]);
        }
#pragma unroll
        for (int i = 0; i < 4; ++i) {
            int node = gbase + tn * 4 + i;
            if (node < N) {
                float o0 = fmaxf(hc[i][0], 0.0f), o1 = fmaxf(hc[i][1], 0.0f);
                float o2 = fmaxf(hc[i][2], 0.0f), o3 = fmaxf(hc[i][3], 0.0f);
                ushort4 ob = {f2bf(o0), f2bf(o1), f2bf(o2), f2bf(o3)};
                *(ushort4*)&hout[(size_t)node * 64 + tc * 4] = ob;
                sv[0] += o0; sv[1] += o1; sv[2] += o2; sv[3] += o3;
                qv[0] += o0 * o0; qv[1] += o1 * o1; qv[2] += o2 * o2; qv[3] += o3 * o3;
            }
        }
    }
#pragma unroll
    for (int off = 16; off < 64; off <<= 1) {
#pragma unroll
        for (int j = 0; j < 4; ++j) {
            sv[j] += __shfl_xor(sv[j], off);
            qv[j] += __shfl_xor(qv[j], off);
        }
    }
    if ((tid & 63) < 16) {
#pragma unroll
        for (int j = 0; j < 4; ++j) {
            atomicAdd(&statS[tc * 4 + j], sv[j]);
            atomicAdd(&statS[64 + tc * 4 + j], qv[j]);
        }
    }
    __syncthreads();
    if (tid < 128) unsafeAtomicAdd(&stats[tid], statS[tid]);
}

// ================= segmented pool (batch sorted), bf16 input =================
__global__ void pool_seg_kernel(const u16* __restrict__ h, const int* __restrict__ batch,
                                float* __restrict__ pool, float* __restrict__ cnt, int N) {
    int lane = threadIdx.x & 63;
    int wave = (blockIdx.x * blockDim.x + threadIdx.x) >> 6;
    int base = wave * 16;
    if (base >= N) return;
    int end = base + 16; if (end > N) end = N;
    int cur = batch[base];
    float acc = 0.0f;
    int run = 0;
    for (int n = base; n < end; n++) {
        int gid = batch[n];
        if (gid != cur) {
            unsafeAtomicAdd(&pool[(size_t)cur * 64 + lane], acc);
            if (lane == 0) unsafeAtomicAdd(&cnt[cur], (float)run);
            acc = 0.0f; run = 0; cur = gid;
        }
        acc += bf2f(h[(size_t)n * 64 + lane]);
        run++;
    }
    unsafeAtomicAdd(&pool[(size_t)cur * 64 + lane], acc);
    if (lane == 0) unsafeAtomicAdd(&cnt[cur], (float)run);
}

// ================= readout (applies BN3 affine to pooled mean) =================
__global__ void readout_kernel(const float* __restrict__ pool, const float* __restrict__ cnt,
                               const float* __restrict__ stats, const float* __restrict__ g3,
                               const float* __restrict__ be3,
                               const float* __restrict__ Wf1, const float* __restrict__ bf1,
                               const float* __restrict__ Wf2, const float* __restrict__ bf2,
                               float* __restrict__ out, int N) {
    int gb = blockIdx.x;
    int t = threadIdx.x;  // 64 threads
    float invN = 1.0f / (float)N;
    float mu = stats[t] * invN;
    float var = stats[64 + t] * invN - mu * mu;
    float inv = rsqrtf(var + 1e-5f);
    float a = g3[t] * inv;
    float c = be3[t] - mu * a;
    float cn = cnt[gb];
    float p = (cn > 0.0f) ? (a * (pool[(size_t)gb * 64 + t] / cn) + c) : 0.0f;
    float o = 0.0f;
#pragma unroll
    for (int j = 0; j < 10; j++) {
        float part = p * Wf1[t * 10 + j];
#pragma unroll
        for (int off = 32; off > 0; off >>= 1) part += __shfl_down(part, off);
        float z = fmaxf(part + bf1[j], 0.0f);   // valid on lane 0 only
        o = fmaf(z, Wf2[j], o);
    }
    if (t == 0) out[gb] = o + bf2[0];
}

extern "C" void kernel_launch(void* const* d_in, const int* in_sizes, int n_in,
                              void* d_out, int out_size, void* d_ws, size_t ws_size,
                              hipStream_t stream) {
    const float* x      = (const float*)d_in[0];
    const int*   ei     = (const int*)d_in[1];
    const int*   batch  = (const int*)d_in[2];
    const float* W1a = (const float*)d_in[3];  const float* b1a = (const float*)d_in[4];
    const float* W1b = (const float*)d_in[5];  const float* b1b = (const float*)d_in[6];
    const float* e1  = (const float*)d_in[7];  const float* g1  = (const float*)d_in[8];
    const float* be1 = (const float*)d_in[9];
    const float* W2a = (const float*)d_in[10]; const float* b2a = (const float*)d_in[11];
    const float* W2b = (const float*)d_in[12]; const float* b2b = (const float*)d_in[13];
    const float* e2  = (const float*)d_in[14]; const float* g2  = (const float*)d_in[15];
    const float* be2 = (const float*)d_in[16];
    const float* W3a = (const float*)d_in[17]; const float* b3a = (const float*)d_in[18];
    const float* W3b = (const float*)d_in[19]; const float* b3b = (const float*)d_in[20];
    const float* e3  = (const float*)d_in[21]; const float* g3  = (const float*)d_in[22];
    const float* be3 = (const float*)d_in[23];
    const float* Wf1 = (const float*)d_in[24]; const float* bf1 = (const float*)d_in[25];
    const float* Wf2 = (const float*)d_in[26]; const float* bf2 = (const float*)d_in[27];

    const int N = in_sizes[2];
    const int E = in_sizes[1] / 2;
    const int G = out_size;
    const int NBUCK = (N + 511) >> BSH;
    const int C = (E + NBLK - 1) / NBLK;

    // ---------- workspace layout ----------
    int* csr       = (int*)d_ws;               // E
    int* row_start = csr + E;                  // N+64
    int* bpack     = row_start + N + 64;       // E
    int* ghist     = bpack + E;                // NBLK*256
    int* total     = ghist + NBLK * 256;       // 256
    int* bbase     = total + 256;              // 272
    // --- contiguous zero-init region ---
    float* stats   = (float*)(bbase + 272);    // 3*128
    float* pool    = stats + 384;              // G*64
    float* cnt     = pool + (size_t)G * HD;    // G
    // --- end zero region ---
    float* aggr    = cnt + G;                  // N*64 f32
    size_t NH = (size_t)N * HD;
    u16* hA        = (u16*)(aggr + NH);        // N*64 bf16
    u16* hB        = hA + NH;                  // N*64 bf16

    const int TB = 256;
    int fusedGrid = (N + 127) / 128;
    size_t zeroBytes = (size_t)(384 + (size_t)G * HD + G) * sizeof(float);

    // ---------- CSR build (deterministic two-pass bucket sort) ----------
    hipMemsetAsync(stats, 0, zeroBytes, stream);
    hist_kernel<<<NBLK, 256, 0, stream>>>(ei, ghist, E, C);
    colscan_kernel<<<NBUCK, 256, 0, stream>>>(ghist, total);
    base_kernel<<<1, 256, 0, stream>>>(total, bbase, NBUCK);
    scatter_kernel<<<NBLK, 256, 0, stream>>>(ei, ghist, bbase, bpack, E, C);
    csrbuild_kernel<<<NBUCK, 256, 0, stream>>>(bpack, bbase, row_start, csr, N);

    // ---------- layer 1: x(16,f32) -> hA(bf16), stats1 ----------
    gather16_kernel<<<((N + 15) / 16 * 64 + TB - 1) / TB, TB, 0, stream>>>(x, row_start, csr, aggr, N);
    fused_mlp_kernel<16, false><<<fusedGrid, TB, 0, stream>>>(
        x, aggr, row_start, W1a, b1a, W1b, b1b, e1, nullptr, nullptr, nullptr, hA, stats, N);

    // ---------- layer 2: hA(bf16) -> hB(bf16), BN1 folded ----------
    gather64_kernel<<<((N + 3) / 4 * 64 + TB - 1) / TB, TB, 0, stream>>>(hA, row_start, csr, aggr, N);
    fused_mlp_kernel<64, true><<<fusedGrid, TB, 0, stream>>>(
        hA, aggr, row_start, W2a, b2a, W2b, b2b, e2, stats, g1, be1, hB, stats + 128, N);

    // ---------- layer 3: hB(bf16) -> hA(bf16), BN2 folded ----------
    gather64_kernel<<<((N + 3) / 4 * 64 + TB - 1) / TB, TB, 0, stream>>>(hB, row_start, csr, aggr, N);
    fused_mlp_kernel<64, true><<<fusedGrid, TB, 0, stream>>>(
        hB, aggr, row_start, W3a, b3a, W3b, b3b, e3, stats + 128, g2, be2, hA, stats + 256, N);

    // ---------- pool raw h3 (BN3 affine applied in readout) ----------
    int poolWaves = (N + 15) / 16;
    pool_seg_kernel<<<(poolWaves * 64 + TB - 1) / TB, TB, 0, stream>>>(hA, batch, pool, cnt, N);
    readout_kernel<<<G, 64, 0, stream>>>(pool, cnt, stats + 256, g3, be3,
                                         Wf1, bf1, Wf2, bf2, (float*)d_out, N);
}